// Round 12
// baseline (193.890 us; speedup 1.0000x reference)
//
#include <hip/hip_runtime.h>

namespace {
constexpr int L_ = 512;
constexpr int B_ = 1024;
constexpr int K_ = 64;
constexpr int START_I = 62;
constexpr int STOP_I = 63;
}

typedef _Float16 h2 __attribute__((ext_vector_type(2)));
typedef unsigned int u32;

#define LOG2E 1.4426950408889634f
#define LN2 0.6931471805599453f

// cvt_pkrtz returns __fp16 ext_vector(2); bit_cast to our h2 (_Float16 x2).
#define CVTPK2(x, y) \
    __builtin_bit_cast(h2, __builtin_amdgcn_cvt_pkrtz((x), (y)))

#if __has_builtin(__builtin_amdgcn_fdot2)
#define FDOT2(a, b, c) __builtin_amdgcn_fdot2((a), (b), (c), false)
#else
#define FDOT2(a, b, c) \
    fmaf((float)(a).x, (float)(b).x, fmaf((float)(a).y, (float)(b).y, (c)))
#endif

// One packed MAC: broadcast pair {p_2k, p_2k+1} (held by even lane 2k) to an
// SGPR, then v_dot2_f32_f16 (2 MACs, scalar src legal in VOP3P).
#define DT(k, ACC)                                                          \
    {                                                                       \
        int s_ = __builtin_amdgcn_readlane(pki, 2 * (k));                   \
        ACC = FDOT2(__builtin_bit_cast(h2, s_), E##k, ACC);                 \
    }

// One forward-recursion step, linear domain:
// p'_i = (sum_j E[i][j] p_j) * exp(emit_i). EREG = emit loaded 4 steps ago.
// Pair-pack: quad_perm[1,0,3,2] DPP gives the pair-neighbor; cvt_pkrtz packs
// {own, nb} — valid on even lanes, which are the only ones read.
// RECEN: every-step exact power-of-2 rescale from lane 0's exponent (keeps
// the f16 pack in range; integer SGPR exponent accumulator, SALU pipe).
#define CRF_STEP(EREG, TNEXT, RECEN)                                        \
    do {                                                                    \
        float ee = exp2f(EREG * LOG2E);                                     \
        {                                                                   \
            int tp = (TNEXT) < len ? (TNEXT) : (len - 1);                   \
            EREG = eb[(long)tp * (B_ * K_)];                                \
        }                                                                   \
        int pi_ = __float_as_int(p);                                        \
        int nbi = __builtin_amdgcn_update_dpp(0, pi_, 0xB1, 0xF, 0xF, false);\
        h2 pk2 = CVTPK2(p, __int_as_float(nbi));                            \
        int pki = __builtin_bit_cast(int, pk2);                             \
        float a0 = 0.f, a1 = 0.f, a2 = 0.f, a3 = 0.f;                       \
        DT(0, a0)  DT(1, a1)  DT(2, a2)  DT(3, a3)                          \
        DT(4, a0)  DT(5, a1)  DT(6, a2)  DT(7, a3)                          \
        DT(8, a0)  DT(9, a1)  DT(10, a2) DT(11, a3)                         \
        DT(12, a0) DT(13, a1) DT(14, a2) DT(15, a3)                         \
        DT(16, a0) DT(17, a1) DT(18, a2) DT(19, a3)                         \
        DT(20, a0) DT(21, a1) DT(22, a2) DT(23, a3)                         \
        DT(24, a0) DT(25, a1) DT(26, a2) DT(27, a3)                         \
        DT(28, a0) DT(29, a1) DT(30, a2) DT(31, a3)                         \
        float pn = ((a0 + a1) + (a2 + a3)) * ee;                            \
        if (RECEN) {                                                        \
            int p0i = __builtin_amdgcn_readfirstlane(__float_as_int(pn));   \
            int kk = ((p0i >> 23) & 0xFF) - 127;                            \
            pn *= __uint_as_float((u32)(127 - kk) << 23);                   \
            base2k += kk;                                                   \
        }                                                                   \
        p = pn;                                                             \
    } while (0)

__global__ __launch_bounds__(64)
__attribute__((amdgpu_waves_per_eu(1, 1)))
void crf_kernel(
    const float* __restrict__ emit,    // (L,B,K)
    const float* __restrict__ trans,   // (K,K)
    const int* __restrict__ labels,    // (L,B)
    const float* __restrict__ masks,   // (L,B)
    float* __restrict__ out)           // (B,)
{
    const int lane = threadIdx.x & 63;
    const int b = blockIdx.x;

    // E row `lane` of exp(T) as 32 named half2 regs (f16 pairs, 32 VGPRs),
    // asm-laundered against rematerialization (proven necessary R2->R5).
    const float4* t4 = reinterpret_cast<const float4*>(trans + lane * K_);
#define MKE(q, A, Bn)                                                       \
    float4 tv##q = t4[q];                                                   \
    h2 A  = CVTPK2(exp2f(tv##q.x * LOG2E), exp2f(tv##q.y * LOG2E));         \
    h2 Bn = CVTPK2(exp2f(tv##q.z * LOG2E), exp2f(tv##q.w * LOG2E));         \
    asm("" : "+v"(A), "+v"(Bn));
    MKE(0, E0, E1)   MKE(1, E2, E3)   MKE(2, E4, E5)   MKE(3, E6, E7)
    MKE(4, E8, E9)   MKE(5, E10, E11) MKE(6, E12, E13) MKE(7, E14, E15)
    MKE(8, E16, E17) MKE(9, E18, E19) MKE(10, E20, E21) MKE(11, E22, E23)
    MKE(12, E24, E25) MKE(13, E26, E27) MKE(14, E28, E29) MKE(15, E30, E31)
#undef MKE

    // len[b] = sum_t masks[t,b] (prefix masks); readfirstlane -> scalar so
    // the per-step clamp + trip count go to the SALU pipe.
    int len = 0;
    #pragma unroll
    for (int c = 0; c < L_ / 64; ++c)
        len += (int)masks[(c * 64 + lane) * B_ + b];
    #pragma unroll
    for (int off = 32; off >= 1; off >>= 1)
        len += __shfl_xor(len, off);
    len = __builtin_amdgcn_readfirstlane(len);

    // Linear-domain state: score_i = (log2 p_i + base2k)*ln2.
    float p = (lane == START_I) ? 1.0f : 0.0f;
    int base2k = 0;
    const float* eb = emit + b * K_ + lane;

    // 4-deep emit prefetch ring (depth proven sufficient R5/R6).
    float e0 = eb[0L * (B_ * K_)];
    float e1 = eb[1L * (B_ * K_)];
    float e2 = eb[2L * (B_ * K_)];
    float e3 = eb[3L * (B_ * K_)];

    // Peel first group: step 0 must not recenter (p one-hot, lane0 = 0).
    CRF_STEP(e0, 4, 0);
    CRF_STEP(e1, 5, 1);
    CRF_STEP(e2, 6, 1);
    CRF_STEP(e3, 7, 1);
    int t = 4;
    for (; t + 4 <= len; t += 4) {
        CRF_STEP(e0, t + 4, 1);
        CRF_STEP(e1, t + 5, 1);
        CRF_STEP(e2, t + 6, 1);
        CRF_STEP(e3, t + 7, 1);
    }
    if (t < len) { CRF_STEP(e0, len - 1, 1); ++t; }
    if (t < len) { CRF_STEP(e1, len - 1, 1); ++t; }
    if (t < len) { CRF_STEP(e2, len - 1, 1); ++t; }

    // partition = LSE_k(score_k + T[STOP,k])
    float base2 = (float)base2k;
    float v = fmaf(__log2f(p) + base2, LN2, trans[STOP_I * K_ + lane]);
    float M = v;
    #pragma unroll
    for (int off = 32; off >= 1; off >>= 1)
        M = fmaxf(M, __shfl_xor(M, off));
    float pe = exp2f((v - M) * LOG2E);
    #pragma unroll
    for (int off = 32; off >= 1; off >>= 1)
        pe += __shfl_xor(pe, off);
    float part = fmaf(__log2f(pe), LN2, M);

    // gold score: lanes cover t = c*64 + lane
    float g = 0.0f;
    #pragma unroll
    for (int c = 0; c < L_ / 64; ++c) {
        int tt = c * 64 + lane;
        if (tt < len) {
            int lt = labels[tt * B_ + b];
            int lp = (tt == 0) ? START_I : labels[(tt - 1) * B_ + b];
            g += trans[lt * K_ + lp] + emit[((long)tt * B_ + b) * K_ + lt];
        }
    }
    #pragma unroll
    for (int off = 32; off >= 1; off >>= 1)
        g += __shfl_xor(g, off);
    int lastl = labels[(len - 1) * B_ + b];
    g += trans[STOP_I * K_ + lastl];

    if (lane == 0) out[b] = part - g;
}

extern "C" void kernel_launch(void* const* d_in, const int* in_sizes, int n_in,
                              void* d_out, int out_size, void* d_ws, size_t ws_size,
                              hipStream_t stream) {
    const float* emit = (const float*)d_in[0];
    const float* trans = (const float*)d_in[1];
    const int* labels = (const int*)d_in[2];
    const float* masks = (const float*)d_in[3];
    float* out = (float*)d_out;
    crf_kernel<<<B_, 64, 0, stream>>>(emit, trans, labels, masks, out);
}

// Round 13
// 192.087 us; speedup vs baseline: 1.0094x; 1.0094x over previous
//
#include <hip/hip_runtime.h>

namespace {
constexpr int L_ = 512;
constexpr int B_ = 1024;
constexpr int K_ = 64;
constexpr int START_I = 62;
constexpr int STOP_I = 63;
}

typedef unsigned int u32;

#define LOG2E 1.4426950408889634f
#define LN2 0.6931471805599453f

__device__ __forceinline__ float bcast0(float x) {
    return __int_as_float(__builtin_amdgcn_readfirstlane(__float_as_int(x)));
}

// One packed broadcast + 2 MACs. readlane fetches the bf16 pair {p_2k,p_2k+1}
// (packed on even lane 2k); unpack is SALU (s_lshl/s_and — exact bf16->f32),
// which issues on the scalar pipe in readlane dead cycles; the 2 fmacs take
// the unpacked values as their single legal scalar operand.
#define DT(k, A_, B_, EL, EH)                                               \
    {                                                                       \
        int s_ = __builtin_amdgcn_readlane(pki, 2 * (k));                   \
        float lo = __int_as_float(s_ << 16);                                \
        float hi = __int_as_float(s_ & 0xFFFF0000);                         \
        A_ = fmaf(lo, EL, A_);                                              \
        B_ = fmaf(hi, EH, B_);                                              \
    }

// One forward-recursion step, linear domain:
// p'_i = (sum_j E[i][j] p_j) * exp(emit_i). EREG = emit loaded 4 steps ago.
// Pair-pack: quad_perm[1,0,3,2] DPP gives the pair-neighbor; cvt_pk_bf16
// (RNE) packs {own, nb} — valid on even lanes, the only ones readlane'd.
// RECEN: every-4-steps exact power-of-2 rescale from lane 0's exponent
// (proven R2/R5; f32 accumulate throughout, only the broadcast is bf16).
#define CRF_STEP(EREG, TNEXT, RECEN)                                        \
    do {                                                                    \
        float ee = exp2f(EREG * LOG2E);                                     \
        {                                                                   \
            int tp = (TNEXT) < len ? (TNEXT) : (len - 1);                   \
            EREG = eb[(long)tp * (B_ * K_)];                                \
        }                                                                   \
        int pi_ = __float_as_int(p);                                        \
        int nbi = __builtin_amdgcn_update_dpp(0, pi_, 0xB1, 0xF, 0xF, false);\
        u32 pki;                                                            \
        asm("v_cvt_pk_bf16_f32 %0, %1, %2"                                  \
            : "=v"(pki) : "v"(p), "v"(__int_as_float(nbi)));                \
        float a0 = 0.f, a1 = 0.f, a2 = 0.f, a3 = 0.f;                       \
        DT(0,  a0, a1, E0,  E1)   DT(1,  a2, a3, E2,  E3)                   \
        DT(2,  a0, a1, E4,  E5)   DT(3,  a2, a3, E6,  E7)                   \
        DT(4,  a0, a1, E8,  E9)   DT(5,  a2, a3, E10, E11)                  \
        DT(6,  a0, a1, E12, E13)  DT(7,  a2, a3, E14, E15)                  \
        DT(8,  a0, a1, E16, E17)  DT(9,  a2, a3, E18, E19)                  \
        DT(10, a0, a1, E20, E21)  DT(11, a2, a3, E22, E23)                  \
        DT(12, a0, a1, E24, E25)  DT(13, a2, a3, E26, E27)                  \
        DT(14, a0, a1, E28, E29)  DT(15, a2, a3, E30, E31)                  \
        DT(16, a0, a1, E32, E33)  DT(17, a2, a3, E34, E35)                  \
        DT(18, a0, a1, E36, E37)  DT(19, a2, a3, E38, E39)                  \
        DT(20, a0, a1, E40, E41)  DT(21, a2, a3, E42, E43)                  \
        DT(22, a0, a1, E44, E45)  DT(23, a2, a3, E46, E47)                  \
        DT(24, a0, a1, E48, E49)  DT(25, a2, a3, E50, E51)                  \
        DT(26, a0, a1, E52, E53)  DT(27, a2, a3, E54, E55)                  \
        DT(28, a0, a1, E56, E57)  DT(29, a2, a3, E58, E59)                  \
        DT(30, a0, a1, E60, E61)  DT(31, a2, a3, E62, E63)                  \
        float pn = ((a0 + a1) + (a2 + a3)) * ee;                            \
        if (RECEN) {                                                        \
            float p0 = bcast0(pn);                                          \
            int kk = (int)(__float_as_uint(p0) >> 23) - 127;                \
            pn *= __uint_as_float((u32)(127 - kk) << 23);                   \
            base2 += (float)kk;                                             \
        }                                                                   \
        p = pn;                                                             \
    } while (0)

__global__ __launch_bounds__(64)
__attribute__((amdgpu_waves_per_eu(1, 1)))
void crf_kernel(
    const float* __restrict__ emit,    // (L,B,K)
    const float* __restrict__ trans,   // (K,K)
    const int* __restrict__ labels,    // (L,B)
    const float* __restrict__ masks,   // (L,B)
    float* __restrict__ out)           // (B,)
{
    const int lane = threadIdx.x & 63;
    const int b = blockIdx.x;

    // E row `lane` of exp(T) in 64 named f32 scalars (VGPR-resident per R5:
    // VGPR_Count 132, asm-laundered against remat).
    const float4* t4 = reinterpret_cast<const float4*>(trans + lane * K_);
#define MKE(q, A, Bn, C, D)                                                 \
    float4 tv##q = t4[q];                                                   \
    float A  = exp2f(tv##q.x * LOG2E);                                      \
    float Bn = exp2f(tv##q.y * LOG2E);                                      \
    float C  = exp2f(tv##q.z * LOG2E);                                      \
    float D  = exp2f(tv##q.w * LOG2E);                                      \
    asm("" : "+v"(A), "+v"(Bn), "+v"(C), "+v"(D));
    MKE(0,  E0,  E1,  E2,  E3)   MKE(1,  E4,  E5,  E6,  E7)
    MKE(2,  E8,  E9,  E10, E11)  MKE(3,  E12, E13, E14, E15)
    MKE(4,  E16, E17, E18, E19)  MKE(5,  E20, E21, E22, E23)
    MKE(6,  E24, E25, E26, E27)  MKE(7,  E28, E29, E30, E31)
    MKE(8,  E32, E33, E34, E35)  MKE(9,  E36, E37, E38, E39)
    MKE(10, E40, E41, E42, E43)  MKE(11, E44, E45, E46, E47)
    MKE(12, E48, E49, E50, E51)  MKE(13, E52, E53, E54, E55)
    MKE(14, E56, E57, E58, E59)  MKE(15, E60, E61, E62, E63)
#undef MKE

    // len[b] = sum_t masks[t,b]  (masks are prefix masks)
    int len = 0;
    #pragma unroll
    for (int c = 0; c < L_ / 64; ++c)
        len += (int)masks[(c * 64 + lane) * B_ + b];
    #pragma unroll
    for (int off = 32; off >= 1; off >>= 1)
        len += __shfl_xor(len, off);
    len = __builtin_amdgcn_readfirstlane(len);

    // Linear-domain state: score_i = (log2 p_i + base2)*ln2.
    float p = (lane == START_I) ? 1.0f : 0.0f;
    float base2 = 0.0f;
    const float* eb = emit + b * K_ + lane;

    // 4-deep emit prefetch ring (depth proven sufficient R5/R6).
    float e0 = eb[0L * (B_ * K_)];
    float e1 = eb[1L * (B_ * K_)];
    float e2 = eb[2L * (B_ * K_)];
    float e3 = eb[3L * (B_ * K_)];

    int t = 0;
    for (; t + 4 <= len; t += 4) {
        CRF_STEP(e0, t + 4, 0);
        CRF_STEP(e1, t + 5, 0);
        CRF_STEP(e2, t + 6, 0);
        CRF_STEP(e3, t + 7, 1);
    }
    if (t < len) { CRF_STEP(e0, len - 1, 1); ++t; }
    if (t < len) { CRF_STEP(e1, len - 1, 1); ++t; }
    if (t < len) { CRF_STEP(e2, len - 1, 1); ++t; }

    // partition = LSE_k(score_k + T[STOP,k])
    float v = fmaf(__log2f(p) + base2, LN2, trans[STOP_I * K_ + lane]);
    float M = v;
    #pragma unroll
    for (int off = 32; off >= 1; off >>= 1)
        M = fmaxf(M, __shfl_xor(M, off));
    float pe = exp2f((v - M) * LOG2E);
    #pragma unroll
    for (int off = 32; off >= 1; off >>= 1)
        pe += __shfl_xor(pe, off);
    float part = fmaf(__log2f(pe), LN2, M);

    // gold score: lanes cover t = c*64 + lane
    float g = 0.0f;
    #pragma unroll
    for (int c = 0; c < L_ / 64; ++c) {
        int tt = c * 64 + lane;
        if (tt < len) {
            int lt = labels[tt * B_ + b];
            int lp = (tt == 0) ? START_I : labels[(tt - 1) * B_ + b];
            g += trans[lt * K_ + lp] + emit[((long)tt * B_ + b) * K_ + lt];
        }
    }
    #pragma unroll
    for (int off = 32; off >= 1; off >>= 1)
        g += __shfl_xor(g, off);
    int lastl = labels[(len - 1) * B_ + b];
    g += trans[STOP_I * K_ + lastl];

    if (lane == 0) out[b] = part - g;
}

extern "C" void kernel_launch(void* const* d_in, const int* in_sizes, int n_in,
                              void* d_out, int out_size, void* d_ws, size_t ws_size,
                              hipStream_t stream) {
    const float* emit = (const float*)d_in[0];
    const float* trans = (const float*)d_in[1];
    const int* labels = (const int*)d_in[2];
    const float* masks = (const float*)d_in[3];
    float* out = (float*)d_out;
    crf_kernel<<<B_, 64, 0, stream>>>(emit, trans, labels, masks, out);
}